// Round 4
// baseline (758.886 us; speedup 1.0000x reference)
//
#include <hip/hip_runtime.h>

typedef _Float16 f16x8 __attribute__((ext_vector_type(8)));
typedef _Float16 f16x4 __attribute__((ext_vector_type(4)));
typedef _Float16 f16x2 __attribute__((ext_vector_type(2)));
typedef float f32x4 __attribute__((ext_vector_type(4)));

#define NB_   8
#define NN_   2000
#define TT_   64
#define FF_   32
#define HH_   128
#define EE_   32000
#define KD    160        // F + H
#define RSTR  192        // swizzled LDS row stride (f16 elems)
#define NODES 32         // nodes per block

__device__ __forceinline__ float fexp2(float v) { return __builtin_amdgcn_exp2f(v); }
__device__ __forceinline__ float frcp(float v)  { return __builtin_amdgcn_rcpf(v); }

// ---- prep: pack pre-scaled [Wih|Whh] -> fp16 [512][160], gcn_W^T -> fp16, bias, deg=0
// gate rows i,f,o: * -1.44269504 ; g rows [256,384): * -2.88539008
__global__ void prep_kernel(const float* __restrict__ Wih, const float* __restrict__ Whh,
                            const float* __restrict__ bih, const float* __restrict__ bhh,
                            const float* __restrict__ gcnW,
                            _Float16* __restrict__ W16, _Float16* __restrict__ Wg16,
                            float* __restrict__ bias, float* __restrict__ deg) {
  int idx = blockIdx.x * 256 + threadIdx.x;
  if (idx < 512 * KD) {
    int col = idx / KD, k = idx % KD;
    float v = (k < 32) ? Wih[col * 32 + k] : Whh[col * 128 + (k - 32)];
    float sc = (col >= 256 && col < 384) ? -2.88539008f : -1.44269504f;
    W16[idx] = (_Float16)(v * sc);
  } else if (idx < 512 * KD + 128 * 128) {
    int i2 = idx - 512 * KD;
    int colg = i2 >> 7, k = i2 & 127;
    Wg16[i2] = (_Float16)gcnW[k * 128 + colg];   // Wg16[c][k] = gcnW[k][c]
  } else if (idx < 512 * KD + 128 * 128 + 512) {
    int i3 = idx - (512 * KD + 128 * 128);
    float sc = (i3 >= 256 && i3 < 384) ? -2.88539008f : -1.44269504f;
    bias[i3] = (bih[i3] + bhh[i3]) * sc;
  } else if (idx < 512 * KD + 128 * 128 + 512 + NN_) {
    deg[idx - (512 * KD + 128 * 128 + 512)] = 0.f;
  }
}

__global__ void deg_kernel(const int* __restrict__ ei, float* __restrict__ deg) {
  int e = blockIdx.x * 256 + threadIdx.x;
  if (e < EE_ + NN_) {
    int d = (e < EE_) ? ei[EE_ + e] : (e - EE_);
    atomicAdd(&deg[d], 1.f);
  }
}

// ---- exclusive scan of (deg-1) + dinv, one block
__global__ void scan_kernel(const float* __restrict__ deg, int* __restrict__ offs,
                            int* __restrict__ cursor, float* __restrict__ dinv) {
  __shared__ int s0[2048], s1[2048];
  int t = threadIdx.x;
  for (int i = t; i < 2048; i += 1024) s0[i] = (i < NN_) ? ((int)deg[i] - 1) : 0;
  __syncthreads();
  int* src = s0; int* dst = s1;
  for (int off = 1; off < 2048; off <<= 1) {
    for (int i = t; i < 2048; i += 1024)
      dst[i] = src[i] + ((i >= off) ? src[i - off] : 0);
    __syncthreads();
    int* tmp = src; src = dst; dst = tmp;
  }
  for (int i = t; i < NN_; i += 1024) {
    int exc = src[i] - ((int)deg[i] - 1);
    offs[i] = exc;
    cursor[i] = exc;
    float d = deg[i];
    dinv[i] = (d > 0.f) ? __builtin_amdgcn_rsqf(d) : 0.f;
  }
}

__global__ void fill_kernel(const int* __restrict__ ei, const float* __restrict__ dinv,
                            int* __restrict__ cursor, int* __restrict__ csr_src,
                            float* __restrict__ csr_w) {
  int e = blockIdx.x * 256 + threadIdx.x;
  if (e >= EE_) return;
  int s = ei[e], d = ei[EE_ + e];
  int pos = atomicAdd(&cursor[d], 1);
  csr_src[pos] = s;
  csr_w[pos] = dinv[s] * dinv[d];
}

// ---- fused LSTM + GCN-GEMM. 500 blocks x 512 thr, 32 nodes; 2 blocks/CU co-resident.
// Round-1 structure (single activation buffer, 2 barriers/step, x-prefetch issued
// between MFMA phase and mid barrier — both empirically best). This round's change:
// the Wx A-frags (ax[4]) and bias init vectors are LOOP-INVARIANT and thread-private;
// they now live in registers loaded once from global, instead of 8 LDS reads per
// wave-step (18 -> 10 ds_reads; LDS read BW was the largest per-CU step cost).
// WxL/BiasL LDS arrays deleted (55.3 KB -> 12.3 KB). Unified reg file at 4 waves/SIMD
// allows 512 regs/wave; we go ~160 -> ~192 — no spill risk.
// Gates: merged-denominator sigmoids, 5 exp2 + 2 rcp per h-elem.
__global__ __launch_bounds__(512, 4) void lstm_gcn_kernel(
    const float* __restrict__ x, const _Float16* __restrict__ W16,
    const float* __restrict__ bias, const _Float16* __restrict__ Wg16,
    float* __restrict__ xwT) {
  __shared__ _Float16 A[NODES * RSTR];      // 12288 B
  const int tid  = threadIdx.x;
  const int wave = tid >> 6;
  const int lane = tid & 63;
  const int n15  = lane & 15;
  const int q    = lane >> 4;
  const int m    = n15 & 7;
  const int hm   = m >> 2;
  const int qx   = q ^ (m & 3);
  const int node0 = blockIdx.x * NODES;

  // resident weight A-frags for K 32..159 (h-part): rows = gate dims g*128+wave*16+n15
  f16x8 Af[4][4];
#pragma unroll
  for (int g = 0; g < 4; ++g) {
    const int row = g * 128 + wave * 16 + n15;
#pragma unroll
    for (int kc = 1; kc < 5; ++kc)
      Af[g][kc - 1] = *(const f16x8*)(W16 + row * KD + kc * 32 + q * 8);
  }
  // resident Wx A-frags (K 0..31) + bias accumulator-init — loop-invariant, thread-private
  f16x8 Ax[4];
  f32x4 Bz[4];
#pragma unroll
  for (int g = 0; g < 4; ++g) {
    const int row = g * 128 + wave * 16 + n15;
    Ax[g] = *(const f16x8*)(W16 + row * KD + q * 8);
    Bz[g] = *(const f32x4*)(bias + g * 128 + wave * 16 + q * 4);
  }

  // per-lane LDS offsets (activation tile, XOR swizzle)
  const int bRow = n15 * RSTR + (qx << 3);   // + ((kc^hm)<<5) + nt*16*RSTR
  const int hOff = n15 * RSTR + (((4 + 2 * wave + (q >> 1)) ^ m) << 3) + ((q & 1) << 2);

  // x staging: thread stages 2 floats of one node-row per step
  const int xrow = tid >> 4;          // 0..31
  const int xf   = (tid & 15) * 2;
  const int xOff = xrow * RSTR + (((xf >> 3) ^ (xrow & 7)) << 3) + (xf & 7);
  const float* xb = x + (size_t)(node0 + xrow) * (TT_ * FF_) + xf;

  // h = 0
  {
    int row = tid >> 4, ci = tid & 15;
    f16x8 z8 = {(_Float16)0, (_Float16)0, (_Float16)0, (_Float16)0,
                (_Float16)0, (_Float16)0, (_Float16)0, (_Float16)0};
    *(f16x8*)(A + row * RSTR + (((4 + ci) ^ (row & 7)) << 3)) = z8;
  }
  // stage x(0)
  {
    float2 v = *(const float2*)xb;
    f16x2 p = {(_Float16)v.x, (_Float16)v.y};
    *(f16x2*)(A + xOff) = p;
  }
  __syncthreads();

  // de-phase co-resident blocks by ~half a step (kept from round 1; harmless)
  if ((blockIdx.x ^ (blockIdx.x >> 8)) & 1) __builtin_amdgcn_s_sleep(40);

  f32x4 acc[2][4], c[2];
  c[0] = (f32x4){0, 0, 0, 0};
  c[1] = (f32x4){0, 0, 0, 0};

  for (int t = 0; t < TT_; ++t) {
    // ---- MFMA phase: z = W·[x;h] + bias
    {
#pragma unroll
      for (int nt = 0; nt < 2; ++nt)
#pragma unroll
        for (int g = 0; g < 4; ++g) acc[nt][g] = Bz[g];
      __builtin_amdgcn_s_setprio(1);
#pragma unroll
      for (int nt = 0; nt < 2; ++nt) {
        f16x8 bf = *(const f16x8*)(A + nt * (16 * RSTR) + bRow + (hm << 5));  // kc=0
#pragma unroll
        for (int g = 0; g < 4; ++g)
          acc[nt][g] = __builtin_amdgcn_mfma_f32_16x16x32_f16(Ax[g], bf, acc[nt][g], 0, 0, 0);
      }
#pragma unroll
      for (int kc = 1; kc < 5; ++kc)
#pragma unroll
        for (int nt = 0; nt < 2; ++nt) {
          f16x8 bf = *(const f16x8*)(A + nt * (16 * RSTR) + bRow + ((kc ^ hm) << 5));
#pragma unroll
          for (int g = 0; g < 4; ++g)
            acc[nt][g] = __builtin_amdgcn_mfma_f32_16x16x32_f16(Af[g][kc - 1], bf, acc[nt][g], 0, 0, 0);
        }
      __builtin_amdgcn_s_setprio(0);
    }
    const bool more = (t + 1 < TT_);
    float2 xv;
    if (more) xv = *(const float2*)(xb + (t + 1) * FF_);
    __syncthreads();   // all LDS reads done before h/x writes

    // ---- gates phase: merged-denominator sigmoids (5 exp2 + 2 rcp per elem).
    // E* = exp2(pre-scaled z) = e^{-z} (g,c scaled by -2.885 -> e^{-2z}):
    //   c' = sf*c + si*tanh(g) = [c*(1+Ei)(1+Eg) + (1-Eg)(1+Ef)] / [(1+Ef)(1+Ei)(1+Eg)]
    //   h  = so*tanh(c')       = (1-Ec) / [(1+Ec)(1+Eo)]
#pragma unroll
    for (int nt = 0; nt < 2; ++nt) {
      f16x4 hp;
#pragma unroll
      for (int r = 0; r < 4; ++r) {
        float Ei = fexp2(acc[nt][0][r]);
        float Ef = fexp2(acc[nt][1][r]);
        float Eg = fexp2(acc[nt][2][r]);
        float Eo = fexp2(acc[nt][3][r]);
        float ai = 1.f + Ei, af = 1.f + Ef, ag = 1.f + Eg, ao = 1.f + Eo;
        float pig = ai * ag;
        float num = c[nt][r] * pig + (1.f - Eg) * af;
        float cn  = num * frcp(af * pig);
        c[nt][r] = cn;
        float Ec = fexp2(-2.88539008f * cn);
        float hn = (1.f - Ec) * frcp((1.f + Ec) * ao);
        hp[r] = (_Float16)hn;
      }
      *(f16x4*)(A + nt * (16 * RSTR) + hOff) = hp;
    }
    if (more) { f16x2 p = {(_Float16)xv.x, (_Float16)xv.y}; *(f16x2*)(A + xOff) = p; }
    __syncthreads();
  }

  // ---- epilogue: xwT[(n*8+b)*128 + col] = sum_k h[node][k] * gcnW[k][col]
  f16x8 Ag[4];
#pragma unroll
  for (int kc = 0; kc < 4; ++kc)
    Ag[kc] = *(const f16x8*)(Wg16 + (wave * 16 + n15) * HH_ + kc * 32 + q * 8);
  f32x4 acc2[2];
  acc2[0] = (f32x4){0, 0, 0, 0};
  acc2[1] = (f32x4){0, 0, 0, 0};
  __builtin_amdgcn_s_setprio(1);
#pragma unroll
  for (int kc = 0; kc < 4; ++kc)
#pragma unroll
    for (int nt = 0; nt < 2; ++nt) {
      f16x8 bf = *(const f16x8*)(A + nt * (16 * RSTR) + bRow + (((kc + 1) ^ hm) << 5));
      acc2[nt] = __builtin_amdgcn_mfma_f32_16x16x32_f16(Ag[kc], bf, acc2[nt], 0, 0, 0);
    }
  __builtin_amdgcn_s_setprio(0);
#pragma unroll
  for (int nt = 0; nt < 2; ++nt) {
    int mnode = node0 + nt * 16 + n15;
    int b = mnode / NN_;
    int n = mnode - b * NN_;
    *(float4*)(xwT + ((size_t)n * 8 + b) * HH_ + wave * 16 + q * 4) =
        (float4){acc2[nt][0], acc2[nt][1], acc2[nt][2], acc2[nt][3]};
  }
}

// ---- fused CSR gather + MLP head: block per dst node; xwT is [node][batch][dim]
__global__ __launch_bounds__(256) void gathermlp_kernel(
    const float* __restrict__ xwT, const int* __restrict__ offs,
    const float* __restrict__ deg, const float* __restrict__ dinv,
    const int* __restrict__ csr_src, const float* __restrict__ csr_w,
    const float* __restrict__ gcnb,
    const float* __restrict__ W1, const float* __restrict__ b1,
    const float* __restrict__ W2, const float* __restrict__ b2,
    float* __restrict__ out) {
  __shared__ float aggs[8][128];
  __shared__ float W1T[64][132];            // W1T[j][k] = W1[k*64+j]; pad 132 vs bank conflicts
  const int d = blockIdx.x;
  const int tid = threadIdx.x;
  for (int i = tid; i < 8192; i += 256) {
    int k = i >> 6, j = i & 63;
    W1T[j][k] = W1[i];
  }
  {
    const int j  = tid & 127;
    const int bh = tid >> 7;                // batch-half: batches bh*4 .. bh*4+3
    const int beg = offs[d];
    const int cnt = (int)deg[d] - 1;
    const int boff = bh * 512 + j;
    float a0 = 0.f, a1 = 0.f, a2 = 0.f, a3 = 0.f;
    int e = 0;
    for (; e + 1 < cnt; e += 2) {           // 2-edge unroll: 8 loads in flight
      int s0 = csr_src[beg + e],     s1 = csr_src[beg + e + 1];
      float w0 = csr_w[beg + e],     w1 = csr_w[beg + e + 1];
      const float* p0 = xwT + (size_t)s0 * 1024 + boff;
      const float* p1 = xwT + (size_t)s1 * 1024 + boff;
      float v00 = p0[0], v01 = p0[128], v02 = p0[256], v03 = p0[384];
      float v10 = p1[0], v11 = p1[128], v12 = p1[256], v13 = p1[384];
      a0 += w0 * v00 + w1 * v10;
      a1 += w0 * v01 + w1 * v11;
      a2 += w0 * v02 + w1 * v12;
      a3 += w0 * v03 + w1 * v13;
    }
    if (e < cnt) {
      int s = csr_src[beg + e];
      float w = csr_w[beg + e];
      const float* p = xwT + (size_t)s * 1024 + boff;
      a0 += w * p[0]; a1 += w * p[128]; a2 += w * p[256]; a3 += w * p[384];
    }
    {
      float di = dinv[d];
      float w = di * di;
      const float* p = xwT + (size_t)d * 1024 + boff;
      a0 += w * p[0]; a1 += w * p[128]; a2 += w * p[256]; a3 += w * p[384];
    }
    float bj = gcnb[j];
    aggs[bh * 4 + 0][j] = a0 + bj;
    aggs[bh * 4 + 1][j] = a1 + bj;
    aggs[bh * 4 + 2][j] = a2 + bj;
    aggs[bh * 4 + 3][j] = a3 + bj;
  }
  __syncthreads();
  // MLP: thread (b = tid>>5, t = tid&31) owns hidden dims {t, t+32}
  const int b = tid >> 5;
  const int t = tid & 31;
  float acc1 = b1[t], acc2 = b1[t + 32];
#pragma unroll 8
  for (int kc = 0; kc < 32; ++kc) {
    float4 a  = *(const float4*)&aggs[b][kc * 4];
    float4 w1 = *(const float4*)&W1T[t][kc * 4];
    float4 w2 = *(const float4*)&W1T[t + 32][kc * 4];
    acc1 += a.x * w1.x + a.y * w1.y + a.z * w1.z + a.w * w1.w;
    acc2 += a.x * w2.x + a.y * w2.y + a.z * w2.z + a.w * w2.w;
  }
  float s1 = acc1 * frcp(1.f + fexp2(-1.44269504f * acc1));
  float s2 = acc2 * frcp(1.f + fexp2(-1.44269504f * acc2));
  float part = s1 * W2[t] + s2 * W2[t + 32];
#pragma unroll
  for (int msk = 16; msk >= 1; msk >>= 1) part += __shfl_xor(part, msk);
  if (t == 0) out[(size_t)b * NN_ + d] = part + b2[0];
}

extern "C" void kernel_launch(void* const* d_in, const int* in_sizes, int n_in,
                              void* d_out, int out_size, void* d_ws, size_t ws_size,
                              hipStream_t stream) {
  const float* x    = (const float*)d_in[0];
  const int*   ei   = (const int*)d_in[1];
  const float* Wih  = (const float*)d_in[2];
  const float* Whh  = (const float*)d_in[3];
  const float* bih  = (const float*)d_in[4];
  const float* bhh  = (const float*)d_in[5];
  const float* gcnW = (const float*)d_in[6];
  const float* gcnb = (const float*)d_in[7];
  const float* W1   = (const float*)d_in[8];
  const float* b1   = (const float*)d_in[9];
  const float* W2   = (const float*)d_in[10];
  const float* b2   = (const float*)d_in[11];
  float* out = (float*)d_out;
  char* ws = (char*)d_ws;

  _Float16* W16    = (_Float16*)(ws);                    // 163840
  _Float16* Wg16   = (_Float16*)(ws + 163840);           // 32768
  float*    bias   = (float*)(ws + 196608);              // 2048
  float*    xwT    = (float*)(ws + 198656);              // 8192000  [node][batch][128]
  float*    deg    = (float*)(ws + 8390656);             // 8192
  float*    dinv   = (float*)(ws + 8398848);             // 8192
  int*      offs   = (int*)(ws + 8407040);               // 8192
  int*      cursor = (int*)(ws + 8415232);               // 8192
  int*      csrs   = (int*)(ws + 8423424);               // 128000
  float*    csrw   = (float*)(ws + 8551424);             // 128000

  prep_kernel<<<394, 256, 0, stream>>>(Wih, Whh, bih, bhh, gcnW, W16, Wg16, bias, deg);
  deg_kernel<<<133, 256, 0, stream>>>(ei, deg);
  scan_kernel<<<1, 1024, 0, stream>>>(deg, offs, cursor, dinv);
  fill_kernel<<<125, 256, 0, stream>>>(ei, dinv, cursor, csrs, csrw);
  lstm_gcn_kernel<<<500, 512, 0, stream>>>(x, W16, bias, Wg16, xwT);
  gathermlp_kernel<<<NN_, 256, 0, stream>>>(xwT, offs, deg, dinv, csrs, csrw,
                                            gcnb, W1, b1, W2, b2, out);
}

// Round 5
// 372.615 us; speedup vs baseline: 2.0366x; 2.0366x over previous
//
#include <hip/hip_runtime.h>

typedef _Float16 f16x8 __attribute__((ext_vector_type(8)));
typedef _Float16 f16x4 __attribute__((ext_vector_type(4)));
typedef _Float16 f16x2 __attribute__((ext_vector_type(2)));
typedef float f32x4 __attribute__((ext_vector_type(4)));

#define NB_   8
#define NN_   2000
#define TT_   64
#define FF_   32
#define HH_   128
#define EE_   32000
#define KD    160        // F + H
#define RSTR  192        // swizzled LDS row stride (f16 elems)
#define NODES 64         // nodes per block (1 block/CU, 250 blocks)

__device__ __forceinline__ float fexp2(float v) { return __builtin_amdgcn_exp2f(v); }
__device__ __forceinline__ float frcp(float v)  { return __builtin_amdgcn_rcpf(v); }

// ---- prep: pack pre-scaled [Wih|Whh] -> fp16 [512][160], gcn_W^T -> fp16, bias, deg=0
// gate rows i,f,o: * -1.44269504 ; g rows [256,384): * -2.88539008
__global__ void prep_kernel(const float* __restrict__ Wih, const float* __restrict__ Whh,
                            const float* __restrict__ bih, const float* __restrict__ bhh,
                            const float* __restrict__ gcnW,
                            _Float16* __restrict__ W16, _Float16* __restrict__ Wg16,
                            float* __restrict__ bias, float* __restrict__ deg) {
  int idx = blockIdx.x * 256 + threadIdx.x;
  if (idx < 512 * KD) {
    int col = idx / KD, k = idx % KD;
    float v = (k < 32) ? Wih[col * 32 + k] : Whh[col * 128 + (k - 32)];
    float sc = (col >= 256 && col < 384) ? -2.88539008f : -1.44269504f;
    W16[idx] = (_Float16)(v * sc);
  } else if (idx < 512 * KD + 128 * 128) {
    int i2 = idx - 512 * KD;
    int colg = i2 >> 7, k = i2 & 127;
    Wg16[i2] = (_Float16)gcnW[k * 128 + colg];   // Wg16[c][k] = gcnW[k][c]
  } else if (idx < 512 * KD + 128 * 128 + 512) {
    int i3 = idx - (512 * KD + 128 * 128);
    float sc = (i3 >= 256 && i3 < 384) ? -2.88539008f : -1.44269504f;
    bias[i3] = (bih[i3] + bhh[i3]) * sc;
  } else if (idx < 512 * KD + 128 * 128 + 512 + NN_) {
    deg[idx - (512 * KD + 128 * 128 + 512)] = 0.f;
  }
}

__global__ void deg_kernel(const int* __restrict__ ei, float* __restrict__ deg) {
  int e = blockIdx.x * 256 + threadIdx.x;
  if (e < EE_ + NN_) {
    int d = (e < EE_) ? ei[EE_ + e] : (e - EE_);
    atomicAdd(&deg[d], 1.f);
  }
}

// ---- exclusive scan of (deg-1) + dinv, one block
__global__ void scan_kernel(const float* __restrict__ deg, int* __restrict__ offs,
                            int* __restrict__ cursor, float* __restrict__ dinv) {
  __shared__ int s0[2048], s1[2048];
  int t = threadIdx.x;
  for (int i = t; i < 2048; i += 1024) s0[i] = (i < NN_) ? ((int)deg[i] - 1) : 0;
  __syncthreads();
  int* src = s0; int* dst = s1;
  for (int off = 1; off < 2048; off <<= 1) {
    for (int i = t; i < 2048; i += 1024)
      dst[i] = src[i] + ((i >= off) ? src[i - off] : 0);
    __syncthreads();
    int* tmp = src; src = dst; dst = tmp;
  }
  for (int i = t; i < NN_; i += 1024) {
    int exc = src[i] - ((int)deg[i] - 1);
    offs[i] = exc;
    cursor[i] = exc;
    float d = deg[i];
    dinv[i] = (d > 0.f) ? __builtin_amdgcn_rsqf(d) : 0.f;
  }
}

__global__ void fill_kernel(const int* __restrict__ ei, const float* __restrict__ dinv,
                            int* __restrict__ cursor, int* __restrict__ csr_src,
                            float* __restrict__ csr_w) {
  int e = blockIdx.x * 256 + threadIdx.x;
  if (e >= EE_) return;
  int s = ei[e], d = ei[EE_ + e];
  int pos = atomicAdd(&cursor[d], 1);
  csr_src[pos] = s;
  csr_w[pos] = dinv[s] * dinv[d];
}

// ---- fused LSTM + GCN-GEMM. 250 blocks x 512 thr, 64 nodes; 1 block/CU, 2 waves/SIMD.
// Occupancy-for-registers trade: __launch_bounds__(512,2) -> 256 regs/wave, so the
// loop-invariant Wx A-frags (Ax) and bias (Bz) are register-resident (loaded once from
// global), and each wave covers 4 node-tiles (nt=0..3). Per-CU-step LDS reads drop
// 288 -> 160 b128 (the former largest per-CU cost); MFMA work unchanged. WxL/BiasL
// LDS arrays deleted. Resident regs ~200/wave: acc 64 + c 16 + Af 64 + Ax 16 + Bz 16.
// (Round-4 lesson: at launch_bounds(512,4) the cap is 128 and this spills 433 MB.)
// Gates: merged-denominator sigmoids, 5 exp2 + 2 rcp per h-elem.
__global__ __launch_bounds__(512, 2) void lstm_gcn_kernel(
    const float* __restrict__ x, const _Float16* __restrict__ W16,
    const float* __restrict__ bias, const _Float16* __restrict__ Wg16,
    float* __restrict__ xwT) {
  __shared__ _Float16 A[NODES * RSTR];      // 24576 B
  const int tid  = threadIdx.x;
  const int wave = tid >> 6;                // 0..7
  const int lane = tid & 63;
  const int n15  = lane & 15;
  const int q    = lane >> 4;
  const int m    = n15 & 7;
  const int hm   = m >> 2;
  const int qx   = q ^ (m & 3);
  const int node0 = blockIdx.x * NODES;

  // resident weight A-frags for K 32..159 (h-part): rows = gate dims g*128+wave*16+n15
  f16x8 Af[4][4];
  // resident Wx A-frags (K 0..31) + bias accumulator-init (loop-invariant, thread-private)
  f16x8 Ax[4];
  f32x4 Bz[4];
#pragma unroll
  for (int g = 0; g < 4; ++g) {
    const int row = g * 128 + wave * 16 + n15;
#pragma unroll
    for (int kc = 1; kc < 5; ++kc)
      Af[g][kc - 1] = *(const f16x8*)(W16 + row * KD + kc * 32 + q * 8);
    Ax[g] = *(const f16x8*)(W16 + row * KD + q * 8);
    Bz[g] = *(const f32x4*)(bias + g * 128 + wave * 16 + q * 4);
  }

  // per-lane LDS offsets (activation tile, XOR swizzle: physical group = logical ^ (row&7))
  const int bRow = n15 * RSTR + (qx << 3);   // + ((kc^hm)<<5) + nt*16*RSTR
  const int hOff = n15 * RSTR + (((4 + 2 * wave + (q >> 1)) ^ m) << 3) + ((q & 1) << 2);

  // x staging: thread stages 4 floats of one node-row per step
  const int xrow = tid >> 3;          // 0..63
  const int xf   = (tid & 7) * 4;     // 0,4,...,28
  const int xOff = xrow * RSTR + (((xf >> 3) ^ (xrow & 7)) << 3) + (xf & 7);
  const float* xb = x + (size_t)(node0 + xrow) * (TT_ * FF_) + xf;

  // h = 0 (64 rows x 16 h-groups = 1024 granules; 2 per thread)
#pragma unroll
  for (int j = 0; j < 2; ++j) {
    int idx = tid * 2 + j;
    int row = idx >> 4, ci = idx & 15;
    f16x8 z8 = {(_Float16)0, (_Float16)0, (_Float16)0, (_Float16)0,
                (_Float16)0, (_Float16)0, (_Float16)0, (_Float16)0};
    *(f16x8*)(A + row * RSTR + (((4 + ci) ^ (row & 7)) << 3)) = z8;
  }
  // stage x(0)
  {
    float4 v = *(const float4*)xb;
    f16x4 p = {(_Float16)v.x, (_Float16)v.y, (_Float16)v.z, (_Float16)v.w};
    *(f16x4*)(A + xOff) = p;
  }
  __syncthreads();

  f32x4 acc[4][4], c[4];
#pragma unroll
  for (int nt = 0; nt < 4; ++nt) c[nt] = (f32x4){0, 0, 0, 0};

  for (int t = 0; t < TT_; ++t) {
    // ---- MFMA phase: z = W·[x;h] + bias
    {
#pragma unroll
      for (int nt = 0; nt < 4; ++nt)
#pragma unroll
        for (int g = 0; g < 4; ++g) acc[nt][g] = Bz[g];
      __builtin_amdgcn_s_setprio(1);
#pragma unroll
      for (int nt = 0; nt < 4; ++nt) {
        f16x8 bf = *(const f16x8*)(A + nt * (16 * RSTR) + bRow + (hm << 5));  // kc=0
#pragma unroll
        for (int g = 0; g < 4; ++g)
          acc[nt][g] = __builtin_amdgcn_mfma_f32_16x16x32_f16(Ax[g], bf, acc[nt][g], 0, 0, 0);
      }
#pragma unroll
      for (int kc = 1; kc < 5; ++kc)
#pragma unroll
        for (int nt = 0; nt < 4; ++nt) {
          f16x8 bf = *(const f16x8*)(A + nt * (16 * RSTR) + bRow + ((kc ^ hm) << 5));
#pragma unroll
          for (int g = 0; g < 4; ++g)
            acc[nt][g] = __builtin_amdgcn_mfma_f32_16x16x32_f16(Af[g][kc - 1], bf, acc[nt][g], 0, 0, 0);
        }
      __builtin_amdgcn_s_setprio(0);
    }
    const bool more = (t + 1 < TT_);
    float4 xv;
    if (more) xv = *(const float4*)(xb + (t + 1) * FF_);
    __syncthreads();   // all LDS reads done before h/x writes

    // ---- gates phase: merged-denominator sigmoids (5 exp2 + 2 rcp per elem).
    // E* = exp2(pre-scaled z) = e^{-z} (g,c scaled by -2.885 -> e^{-2z}):
    //   c' = sf*c + si*tanh(g) = [c*(1+Ei)(1+Eg) + (1-Eg)(1+Ef)] / [(1+Ef)(1+Ei)(1+Eg)]
    //   h  = so*tanh(c')       = (1-Ec) / [(1+Ec)(1+Eo)]
#pragma unroll
    for (int nt = 0; nt < 4; ++nt) {
      f16x4 hp;
#pragma unroll
      for (int r = 0; r < 4; ++r) {
        float Ei = fexp2(acc[nt][0][r]);
        float Ef = fexp2(acc[nt][1][r]);
        float Eg = fexp2(acc[nt][2][r]);
        float Eo = fexp2(acc[nt][3][r]);
        float ai = 1.f + Ei, af = 1.f + Ef, ag = 1.f + Eg, ao = 1.f + Eo;
        float pig = ai * ag;
        float num = c[nt][r] * pig + (1.f - Eg) * af;
        float cn  = num * frcp(af * pig);
        c[nt][r] = cn;
        float Ec = fexp2(-2.88539008f * cn);
        float hn = (1.f - Ec) * frcp((1.f + Ec) * ao);
        hp[r] = (_Float16)hn;
      }
      *(f16x4*)(A + nt * (16 * RSTR) + hOff) = hp;
    }
    if (more) {
      f16x4 p = {(_Float16)xv.x, (_Float16)xv.y, (_Float16)xv.z, (_Float16)xv.w};
      *(f16x4*)(A + xOff) = p;
    }
    __syncthreads();
  }

  // ---- epilogue: xwT[(n*8+b)*128 + col] = sum_k h[node][k] * gcnW[k][col]
  f16x8 Ag[4];
#pragma unroll
  for (int kc = 0; kc < 4; ++kc)
    Ag[kc] = *(const f16x8*)(Wg16 + (wave * 16 + n15) * HH_ + kc * 32 + q * 8);
  f32x4 acc2[4];
#pragma unroll
  for (int nt = 0; nt < 4; ++nt) acc2[nt] = (f32x4){0, 0, 0, 0};
  __builtin_amdgcn_s_setprio(1);
#pragma unroll
  for (int kc = 0; kc < 4; ++kc)
#pragma unroll
    for (int nt = 0; nt < 4; ++nt) {
      f16x8 bf = *(const f16x8*)(A + nt * (16 * RSTR) + bRow + (((kc + 1) ^ hm) << 5));
      acc2[nt] = __builtin_amdgcn_mfma_f32_16x16x32_f16(Ag[kc], bf, acc2[nt], 0, 0, 0);
    }
  __builtin_amdgcn_s_setprio(0);
#pragma unroll
  for (int nt = 0; nt < 4; ++nt) {
    int mnode = node0 + nt * 16 + n15;
    int b = mnode / NN_;
    int n = mnode - b * NN_;
    *(float4*)(xwT + ((size_t)n * 8 + b) * HH_ + wave * 16 + q * 4) =
        (float4){acc2[nt][0], acc2[nt][1], acc2[nt][2], acc2[nt][3]};
  }
}

// ---- fused CSR gather + MLP head: block per dst node; xwT is [node][batch][dim]
__global__ __launch_bounds__(256) void gathermlp_kernel(
    const float* __restrict__ xwT, const int* __restrict__ offs,
    const float* __restrict__ deg, const float* __restrict__ dinv,
    const int* __restrict__ csr_src, const float* __restrict__ csr_w,
    const float* __restrict__ gcnb,
    const float* __restrict__ W1, const float* __restrict__ b1,
    const float* __restrict__ W2, const float* __restrict__ b2,
    float* __restrict__ out) {
  __shared__ float aggs[8][128];
  __shared__ float W1T[64][132];            // W1T[j][k] = W1[k*64+j]; pad 132 vs bank conflicts
  const int d = blockIdx.x;
  const int tid = threadIdx.x;
  for (int i = tid; i < 8192; i += 256) {
    int k = i >> 6, j = i & 63;
    W1T[j][k] = W1[i];
  }
  {
    const int j  = tid & 127;
    const int bh = tid >> 7;                // batch-half: batches bh*4 .. bh*4+3
    const int beg = offs[d];
    const int cnt = (int)deg[d] - 1;
    const int boff = bh * 512 + j;
    float a0 = 0.f, a1 = 0.f, a2 = 0.f, a3 = 0.f;
    int e = 0;
    for (; e + 1 < cnt; e += 2) {           // 2-edge unroll: 8 loads in flight
      int s0 = csr_src[beg + e],     s1 = csr_src[beg + e + 1];
      float w0 = csr_w[beg + e],     w1 = csr_w[beg + e + 1];
      const float* p0 = xwT + (size_t)s0 * 1024 + boff;
      const float* p1 = xwT + (size_t)s1 * 1024 + boff;
      float v00 = p0[0], v01 = p0[128], v02 = p0[256], v03 = p0[384];
      float v10 = p1[0], v11 = p1[128], v12 = p1[256], v13 = p1[384];
      a0 += w0 * v00 + w1 * v10;
      a1 += w0 * v01 + w1 * v11;
      a2 += w0 * v02 + w1 * v12;
      a3 += w0 * v03 + w1 * v13;
    }
    if (e < cnt) {
      int s = csr_src[beg + e];
      float w = csr_w[beg + e];
      const float* p = xwT + (size_t)s * 1024 + boff;
      a0 += w * p[0]; a1 += w * p[128]; a2 += w * p[256]; a3 += w * p[384];
    }
    {
      float di = dinv[d];
      float w = di * di;
      const float* p = xwT + (size_t)d * 1024 + boff;
      a0 += w * p[0]; a1 += w * p[128]; a2 += w * p[256]; a3 += w * p[384];
    }
    float bj = gcnb[j];
    aggs[bh * 4 + 0][j] = a0 + bj;
    aggs[bh * 4 + 1][j] = a1 + bj;
    aggs[bh * 4 + 2][j] = a2 + bj;
    aggs[bh * 4 + 3][j] = a3 + bj;
  }
  __syncthreads();
  // MLP: thread (b = tid>>5, t = tid&31) owns hidden dims {t, t+32}
  const int b = tid >> 5;
  const int t = tid & 31;
  float acc1 = b1[t], acc2 = b1[t + 32];
#pragma unroll 8
  for (int kc = 0; kc < 32; ++kc) {
    float4 a  = *(const float4*)&aggs[b][kc * 4];
    float4 w1 = *(const float4*)&W1T[t][kc * 4];
    float4 w2 = *(const float4*)&W1T[t + 32][kc * 4];
    acc1 += a.x * w1.x + a.y * w1.y + a.z * w1.z + a.w * w1.w;
    acc2 += a.x * w2.x + a.y * w2.y + a.z * w2.z + a.w * w2.w;
  }
  float s1 = acc1 * frcp(1.f + fexp2(-1.44269504f * acc1));
  float s2 = acc2 * frcp(1.f + fexp2(-1.44269504f * acc2));
  float part = s1 * W2[t] + s2 * W2[t + 32];
#pragma unroll
  for (int msk = 16; msk >= 1; msk >>= 1) part += __shfl_xor(part, msk);
  if (t == 0) out[(size_t)b * NN_ + d] = part + b2[0];
}

extern "C" void kernel_launch(void* const* d_in, const int* in_sizes, int n_in,
                              void* d_out, int out_size, void* d_ws, size_t ws_size,
                              hipStream_t stream) {
  const float* x    = (const float*)d_in[0];
  const int*   ei   = (const int*)d_in[1];
  const float* Wih  = (const float*)d_in[2];
  const float* Whh  = (const float*)d_in[3];
  const float* bih  = (const float*)d_in[4];
  const float* bhh  = (const float*)d_in[5];
  const float* gcnW = (const float*)d_in[6];
  const float* gcnb = (const float*)d_in[7];
  const float* W1   = (const float*)d_in[8];
  const float* b1   = (const float*)d_in[9];
  const float* W2   = (const float*)d_in[10];
  const float* b2   = (const float*)d_in[11];
  float* out = (float*)d_out;
  char* ws = (char*)d_ws;

  _Float16* W16    = (_Float16*)(ws);                    // 163840
  _Float16* Wg16   = (_Float16*)(ws + 163840);           // 32768
  float*    bias   = (float*)(ws + 196608);              // 2048
  float*    xwT    = (float*)(ws + 198656);              // 8192000  [node][batch][128]
  float*    deg    = (float*)(ws + 8390656);             // 8192
  float*    dinv   = (float*)(ws + 8398848);             // 8192
  int*      offs   = (int*)(ws + 8407040);               // 8192
  int*      cursor = (int*)(ws + 8415232);               // 8192
  int*      csrs   = (int*)(ws + 8423424);               // 128000
  float*    csrw   = (float*)(ws + 8551424);             // 128000

  prep_kernel<<<394, 256, 0, stream>>>(Wih, Whh, bih, bhh, gcnW, W16, Wg16, bias, deg);
  deg_kernel<<<133, 256, 0, stream>>>(ei, deg);
  scan_kernel<<<1, 1024, 0, stream>>>(deg, offs, cursor, dinv);
  fill_kernel<<<125, 256, 0, stream>>>(ei, dinv, cursor, csrs, csrw);
  lstm_gcn_kernel<<<250, 512, 0, stream>>>(x, W16, bias, Wg16, xwT);
  gathermlp_kernel<<<NN_, 256, 0, stream>>>(xwT, offs, deg, dinv, csrs, csrw,
                                            gcnb, W1, b1, W2, b2, out);
}